// Round 1
// baseline (854.972 us; speedup 1.0000x reference)
//
#include <hip/hip_runtime.h>

// ---------------- common helpers ----------------
typedef __attribute__((ext_vector_type(8))) short short8;
typedef __attribute__((ext_vector_type(4))) float f32x4;

#define B_SZ 512
#define T_SZ 512
#define D_SZ 128
#define M_SZ (B_SZ * T_SZ)   // 262144 rows

__device__ __forceinline__ unsigned short f2bf(float f) {
    union { float f; unsigned u; } v; v.f = f;
    unsigned r = v.u + 0x7FFFu + ((v.u >> 16) & 1u);   // RNE
    return (unsigned short)(r >> 16);
}
__device__ __forceinline__ float bf2f(unsigned short b) {
    union { unsigned u; float f; } v; v.u = ((unsigned)b) << 16;
    return v.f;
}
__device__ __forceinline__ float rcp_(float x) { return __builtin_amdgcn_rcpf(x); }
__device__ __forceinline__ float sigm_(float x) { return rcp_(1.f + __expf(-x)); }
__device__ __forceinline__ float tanh_s(float x) {   // overflow-safe tanh
    float ax = fminf(fabsf(x), 15.f);
    float e2 = __expf(2.f * ax);
    float t = (e2 - 1.f) * rcp_(e2 + 1.f);
    return x < 0.f ? -t : t;
}

// ---------------- weight prep: concat fwd/bwd w_ih -> bf16 [8H][K], bias = b_ih+b_hh ----------------
__global__ __launch_bounds__(256) void prep_layer(
        const float* __restrict__ wf, const float* __restrict__ wb,
        const float* __restrict__ bif, const float* __restrict__ bhf,
        const float* __restrict__ bib, const float* __restrict__ bhb,
        unsigned short* __restrict__ wcat, float* __restrict__ bias,
        int n /*4H*K*/, int fourH) {
    int stride = gridDim.x * blockDim.x;
    for (int i = blockIdx.x * blockDim.x + threadIdx.x; i < 2 * n; i += stride)
        wcat[i] = f2bf(i < n ? wf[i] : wb[i - n]);
    for (int i = blockIdx.x * blockDim.x + threadIdx.x; i < 2 * fourH; i += stride)
        bias[i] = (i < fourH) ? (bif[i] + bhf[i]) : (bib[i - fourH] + bhb[i - fourH]);
}

// ---------------- cast x f32 -> bf16 ----------------
__global__ __launch_bounds__(256) void cast_x_kernel(const float* __restrict__ x,
                                                     unsigned short* __restrict__ o, int n8) {
    int i = blockIdx.x * 256 + threadIdx.x;
    if (i >= n8) return;
    const float4* p = (const float4*)(x + (size_t)i * 8);
    float4 a = p[0], b = p[1];
    short8 r;
    r[0] = (short)f2bf(a.x); r[1] = (short)f2bf(a.y); r[2] = (short)f2bf(a.z); r[3] = (short)f2bf(a.w);
    r[4] = (short)f2bf(b.x); r[5] = (short)f2bf(b.y); r[6] = (short)f2bf(b.z); r[7] = (short)f2bf(b.w);
    *(short8*)(o + (size_t)i * 8) = r;
}

// ---------------- gx GEMM: gx[M][N] = A[M][K] @ Wcat[N][K]^T + bias, all bf16 in, bf16 out ----------------
// One wave computes a 64(M)x16(N) strip: 4 M-tiles sharing one B fragment per K-step.
template<int K, int N>
__global__ __launch_bounds__(256) void gemm_gx(const unsigned short* __restrict__ A,
                                               const unsigned short* __restrict__ W,
                                               const float* __restrict__ bias,
                                               unsigned short* __restrict__ out) {
    constexpr int TN = N / 16;
    int slot = threadIdx.x >> 6, l = threadIdx.x & 63;
    int wv = blockIdx.x * 4 + slot;
    int tg = wv / TN;               // 64-row group
    int tn = wv % TN;
    int rowb = tg * 64;
    int col = tn * 16 + (l & 15);
    int kq = (l >> 4) * 8;
    f32x4 acc0 = {0,0,0,0}, acc1 = {0,0,0,0}, acc2 = {0,0,0,0}, acc3 = {0,0,0,0};
    const unsigned short* wp = W + (size_t)col * K + kq;
    const unsigned short* ap = A + ((size_t)rowb + (l & 15)) * K + kq;
#pragma unroll
    for (int kk = 0; kk < K; kk += 32) {
        short8 bfrag = *(const short8*)(wp + kk);
        short8 a0 = *(const short8*)(ap + kk);
        short8 a1 = *(const short8*)(ap + (size_t)16 * K + kk);
        short8 a2 = *(const short8*)(ap + (size_t)32 * K + kk);
        short8 a3 = *(const short8*)(ap + (size_t)48 * K + kk);
        acc0 = __builtin_amdgcn_mfma_f32_16x16x32_bf16(a0, bfrag, acc0, 0, 0, 0);
        acc1 = __builtin_amdgcn_mfma_f32_16x16x32_bf16(a1, bfrag, acc1, 0, 0, 0);
        acc2 = __builtin_amdgcn_mfma_f32_16x16x32_bf16(a2, bfrag, acc2, 0, 0, 0);
        acc3 = __builtin_amdgcn_mfma_f32_16x16x32_bf16(a3, bfrag, acc3, 0, 0, 0);
    }
    float bv = bias[col];
    int r0 = rowb + (l >> 4) * 4;
#pragma unroll
    for (int r = 0; r < 4; r++) {
        out[((size_t)(r0 + r)) * N + col]      = f2bf(acc0[r] + bv);
        out[((size_t)(r0 + 16 + r)) * N + col] = f2bf(acc1[r] + bv);
        out[((size_t)(r0 + 32 + r)) * N + col] = f2bf(acc2[r] + bv);
        out[((size_t)(r0 + 48 + r)) * N + col] = f2bf(acc3[r] + bv);
    }
}

// ---------------- LSTM scan: one wave per (batch, direction), wave-synchronous ----------------
// gx: bf16 [M][8H] (cols 0..4H-1 fwd gates, 4H..8H-1 bwd gates; gate order i,f,g,o)
// hout: bf16 [M][2H] (cols 0..H-1 fwd, H..2H-1 bwd)
template<int H>
__global__ __launch_bounds__(256) void lstm_scan(const unsigned short* __restrict__ gx,
                                                 const float* __restrict__ whhf,
                                                 const float* __restrict__ whhb,
                                                 unsigned short* __restrict__ hout) {
    constexpr int T = T_SZ;
    constexpr int GXW = 8 * H, OW = 2 * H;
    int l = threadIdx.x & 63, slot = threadIdx.x >> 6;
    int wv = blockIdx.x * 4 + slot;          // 0..1023
    int b = wv >> 1, dir = wv & 1;
    const float* whh = dir ? whhb : whhf;
    __shared__ float hs[4][32];

    int rA, j, q = 0;
    if constexpr (H == 32)      { rA = l;      j = l & 31; }
    else if constexpr (H == 16) { rA = l;      j = l & 15; q = l >> 4; }
    else                        { rA = l & 31; j = l & 7;  q = (l >> 3) & 3; }

    float wA[H];
#pragma unroll
    for (int k = 0; k < H; k++) wA[k] = whh[rA * H + k];
    float wB[(H == 32) ? 32 : 1];
    if constexpr (H == 32) {
#pragma unroll
        for (int k = 0; k < H; k++) wB[k] = whh[(64 + rA) * H + k];
    }

    if (l < H) hs[slot][l] = 0.f;
    __builtin_amdgcn_wave_barrier();

    float c = 0.f;
    size_t gbase = (size_t)b * T * GXW + (size_t)dir * 4 * H;
    int t0 = dir ? (T - 1) : 0;
    int tstep = dir ? -1 : 1;
    unsigned short pA = gx[gbase + (size_t)t0 * GXW + rA];
    unsigned short pB = 0;
    if constexpr (H == 32) pB = gx[gbase + (size_t)t0 * GXW + 64 + rA];

    for (int s = 0; s < T; s++) {
        int t = t0 + s * tstep;
        float g0 = bf2f(pA), g1 = 0.f;
        if constexpr (H == 32) g1 = bf2f(pB);
        if (s + 1 < T) {                       // prefetch next step's gx
            size_t nb = gbase + (size_t)(t + tstep) * GXW;
            pA = gx[nb + rA];
            if constexpr (H == 32) pB = gx[nb + 64 + rA];
        }
        float hv[H];
#pragma unroll
        for (int k = 0; k < H; k += 4) {
            float4 v = *(const float4*)&hs[slot][k];
            hv[k] = v.x; hv[k + 1] = v.y; hv[k + 2] = v.z; hv[k + 3] = v.w;
        }
#pragma unroll
        for (int k = 0; k < H; k++) {
            g0 = fmaf(wA[k], hv[k], g0);
            if constexpr (H == 32) g1 = fmaf(wB[k], hv[k], g1);
        }

        float iv, fv, gv, ov;
        if constexpr (H == 32) {
            // lanes 0-31: aA=i(sigm), aB=g(tanh); lanes 32-63: aA=f(sigm), aB=o(sigm)
            float aA = sigm_(g0);
            bool up = (l >= 32);
            float g1c = fminf(fmaxf(g1, -15.f), 15.f);
            float ee = __expf(up ? -g1 : 2.f * g1c);
            float r = rcp_(1.f + ee);
            float aB = up ? r : (ee - 1.f) * r;
            float xA = __shfl_xor(aA, 32, 64);
            float xB = __shfl_xor(aB, 32, 64);
            iv = up ? xA : aA;
            fv = up ? aA : xA;
            gv = up ? xB : aB;
            ov = up ? aB : xB;
        } else {
            // one gate per lane; quarter q in {0,1,2,3} = {i,f,g,o}
            float g0c = fminf(fmaxf(g0, -15.f), 15.f);
            float ee = __expf(q == 2 ? 2.f * g0c : -g0);
            float r = rcp_(1.f + ee);
            float a = (q == 2) ? (ee - 1.f) * r : r;
            constexpr int sh = H;  // 16 or 8
            float v1 = __shfl_xor(a, sh, 64);       // q^1
            float v2 = __shfl_xor(a, 2 * sh, 64);   // q^2
            float v3 = __shfl_xor(a, 3 * sh, 64);   // q^3
            iv = q == 0 ? a  : q == 1 ? v1 : q == 2 ? v2 : v3;
            fv = q == 0 ? v1 : q == 1 ? a  : q == 2 ? v3 : v2;
            gv = q == 0 ? v2 : q == 1 ? v3 : q == 2 ? a  : v1;
            ov = q == 0 ? v3 : q == 1 ? v2 : q == 2 ? v1 : a;
        }

        c = fmaf(fv, c, iv * gv);
        float h = ov * tanh_s(c);

        bool wr;
        if constexpr (H == 32)      wr = (l < 32);
        else if constexpr (H == 16) wr = (l < 16);
        else                        wr = (l < 8);
        if (wr) {
            hs[slot][j] = h;
            hout[((size_t)b * T + t) * OW + (size_t)dir * H + j] = f2bf(h);
        }
        __builtin_amdgcn_wave_barrier();
    }
}

// ---------------- FC + softmax over time axis (dim=1) ----------------
__global__ __launch_bounds__(256) void fc_softmax(const unsigned short* __restrict__ h3,
                                                  const float* __restrict__ fcw,
                                                  const float* __restrict__ fcb,
                                                  float* __restrict__ out) {
    constexpr int T = T_SZ;
    __shared__ float ez[T][6];
    __shared__ float ps[256][6];
    __shared__ float wf[6][16];
    __shared__ float bb[6];
    int b = blockIdx.x, tid = threadIdx.x;
    if (tid < 96) wf[tid >> 4][tid & 15] = fcw[tid];
    if (tid < 6) bb[tid] = fcb[tid];
    __syncthreads();
#pragma unroll
    for (int ii = 0; ii < 2; ii++) {
        int t = tid + ii * 256;
        const unsigned short* hp = h3 + ((size_t)b * T + t) * 16;
        float hv[16];
#pragma unroll
        for (int k = 0; k < 16; k++) hv[k] = bf2f(hp[k]);
#pragma unroll
        for (int cc = 0; cc < 6; cc++) {
            float z = bb[cc];
#pragma unroll
            for (int k = 0; k < 16; k++) z = fmaf(hv[k], wf[cc][k], z);
            ez[t][cc] = __expf(z);   // |z| <= ~4.5, no overflow; max-subtract not needed
        }
    }
    __syncthreads();
#pragma unroll
    for (int cc = 0; cc < 6; cc++) ps[tid][cc] = ez[tid][cc] + ez[tid + 256][cc];
    __syncthreads();
    for (int s = 128; s > 0; s >>= 1) {
        if (tid < s) {
#pragma unroll
            for (int cc = 0; cc < 6; cc++) ps[tid][cc] += ps[tid + s][cc];
        }
        __syncthreads();
    }
    float rs[6];
#pragma unroll
    for (int cc = 0; cc < 6; cc++) rs[cc] = rcp_(ps[0][cc]);
#pragma unroll
    for (int ii = 0; ii < 2; ii++) {
        int t = tid + ii * 256;
        float* op = out + ((size_t)b * T + t) * 6;
#pragma unroll
        for (int cc = 0; cc < 6; cc++) op[cc] = ez[t][cc] * rs[cc];
    }
}

// ---------------- launch ----------------
extern "C" void kernel_launch(void* const* d_in, const int* in_sizes, int n_in,
                              void* d_out, int out_size, void* d_ws, size_t ws_size,
                              hipStream_t stream) {
    const float* x     = (const float*)d_in[0];
    const float* whh1f = (const float*)d_in[2];
    const float* whh1b = (const float*)d_in[6];
    const float* whh2f = (const float*)d_in[10];
    const float* whh2b = (const float*)d_in[14];
    const float* whh3f = (const float*)d_in[18];
    const float* whh3b = (const float*)d_in[22];
    const float* fcw   = (const float*)d_in[25];
    const float* fcb   = (const float*)d_in[26];

    char* ws = (char*)d_ws;
    size_t off = 0;
    auto alloc = [&](size_t bytes) -> char* {
        char* p = ws + off; off += (bytes + 255) & ~(size_t)255; return p;
    };
    unsigned short* xbf = (unsigned short*)alloc((size_t)M_SZ * 128 * 2);
    unsigned short* gx  = (unsigned short*)alloc((size_t)M_SZ * 256 * 2);
    unsigned short* h1  = (unsigned short*)alloc((size_t)M_SZ * 64 * 2);
    unsigned short* h2  = (unsigned short*)alloc((size_t)M_SZ * 32 * 2);
    unsigned short* h3  = (unsigned short*)alloc((size_t)M_SZ * 16 * 2);
    unsigned short* wc1 = (unsigned short*)alloc(256 * 128 * 2);
    unsigned short* wc2 = (unsigned short*)alloc(128 * 64 * 2);
    unsigned short* wc3 = (unsigned short*)alloc(64 * 32 * 2);
    float* bs1 = (float*)alloc(256 * 4);
    float* bs2 = (float*)alloc(128 * 4);
    float* bs3 = (float*)alloc(64 * 4);

    prep_layer<<<16, 256, 0, stream>>>((const float*)d_in[1], (const float*)d_in[5],
                                       (const float*)d_in[3], (const float*)d_in[4],
                                       (const float*)d_in[7], (const float*)d_in[8],
                                       wc1, bs1, 128 * 128, 128);
    prep_layer<<<16, 256, 0, stream>>>((const float*)d_in[9], (const float*)d_in[13],
                                       (const float*)d_in[11], (const float*)d_in[12],
                                       (const float*)d_in[15], (const float*)d_in[16],
                                       wc2, bs2, 64 * 64, 64);
    prep_layer<<<16, 256, 0, stream>>>((const float*)d_in[17], (const float*)d_in[21],
                                       (const float*)d_in[19], (const float*)d_in[20],
                                       (const float*)d_in[23], (const float*)d_in[24],
                                       wc3, bs3, 32 * 32, 32);

    cast_x_kernel<<<(M_SZ * 128 / 8 + 255) / 256, 256, 0, stream>>>(x, xbf, M_SZ * 128 / 8);

    // Layer 1: K=128, 8H=256
    gemm_gx<128, 256><<<(M_SZ / 64) * 16 / 4, 256, 0, stream>>>(xbf, wc1, bs1, gx);
    lstm_scan<32><<<256, 256, 0, stream>>>(gx, whh1f, whh1b, h1);
    // Layer 2: K=64, 8H=128
    gemm_gx<64, 128><<<(M_SZ / 64) * 8 / 4, 256, 0, stream>>>(h1, wc2, bs2, gx);
    lstm_scan<16><<<256, 256, 0, stream>>>(gx, whh2f, whh2b, h2);
    // Layer 3: K=32, 8H=64
    gemm_gx<32, 64><<<(M_SZ / 64) * 4 / 4, 256, 0, stream>>>(h2, wc3, bs3, gx);
    lstm_scan<8><<<256, 256, 0, stream>>>(gx, whh3f, whh3b, h3);

    fc_softmax<<<B_SZ, 256, 0, stream>>>(h3, fcw, fcb, (float*)d_out);
}

// Round 2
// 685.377 us; speedup vs baseline: 1.2474x; 1.2474x over previous
//
#include <hip/hip_runtime.h>

// ---------------- common helpers ----------------
typedef __attribute__((ext_vector_type(8))) short short8;
typedef __attribute__((ext_vector_type(4))) float f32x4;
typedef __attribute__((ext_vector_type(4))) unsigned short us4;

#define B_SZ 512
#define T_SZ 512
#define D_SZ 128
#define M_SZ (B_SZ * T_SZ)   // 262144 rows

__device__ __forceinline__ unsigned short f2bf(float f) {
    union { float f; unsigned u; } v; v.f = f;
    unsigned r = v.u + 0x7FFFu + ((v.u >> 16) & 1u);   // RNE
    return (unsigned short)(r >> 16);
}
__device__ __forceinline__ float bf2f(unsigned short b) {
    union { unsigned u; float f; } v; v.u = ((unsigned)b) << 16;
    return v.f;
}
__device__ __forceinline__ float rcp_(float x) { return __builtin_amdgcn_rcpf(x); }
__device__ __forceinline__ float sigm_(float x) { return rcp_(1.f + __expf(-x)); }
__device__ __forceinline__ float tanh_s(float x) {   // overflow-safe tanh
    float ax = fminf(fabsf(x), 15.f);
    float e2 = __expf(2.f * ax);
    float t = (e2 - 1.f) * rcp_(e2 + 1.f);
    return x < 0.f ? -t : t;
}

// ---------------- weight prep: concat fwd/bwd w_ih -> bf16 [8H][K], bias = b_ih+b_hh ----------------
__global__ __launch_bounds__(256) void prep_layer(
        const float* __restrict__ wf, const float* __restrict__ wb,
        const float* __restrict__ bif, const float* __restrict__ bhf,
        const float* __restrict__ bib, const float* __restrict__ bhb,
        unsigned short* __restrict__ wcat, float* __restrict__ bias,
        int n /*4H*K*/, int fourH) {
    int stride = gridDim.x * blockDim.x;
    for (int i = blockIdx.x * blockDim.x + threadIdx.x; i < 2 * n; i += stride)
        wcat[i] = f2bf(i < n ? wf[i] : wb[i - n]);
    for (int i = blockIdx.x * blockDim.x + threadIdx.x; i < 2 * fourH; i += stride)
        bias[i] = (i < fourH) ? (bif[i] + bhf[i]) : (bib[i - fourH] + bhb[i - fourH]);
}

// ---------------- cast x f32 -> bf16 ----------------
__global__ __launch_bounds__(256) void cast_x_kernel(const float* __restrict__ x,
                                                     unsigned short* __restrict__ o, int n8) {
    int i = blockIdx.x * 256 + threadIdx.x;
    if (i >= n8) return;
    const float4* p = (const float4*)(x + (size_t)i * 8);
    float4 a = p[0], b = p[1];
    short8 r;
    r[0] = (short)f2bf(a.x); r[1] = (short)f2bf(a.y); r[2] = (short)f2bf(a.z); r[3] = (short)f2bf(a.w);
    r[4] = (short)f2bf(b.x); r[5] = (short)f2bf(b.y); r[6] = (short)f2bf(b.z); r[7] = (short)f2bf(b.w);
    *(short8*)(o + (size_t)i * 8) = r;
}

// ---------------- gx GEMM -> TRANSPOSED output ----------------
// gxT[b][g][t]: g in [0,N) (cols 0..N/2-1 = fwd gates, N/2.. = bwd gates).
// Backward-gate rows are stored TIME-REVERSED so the scan always reads forward.
// One wave computes a 64(M)x16(N) strip: 4 M-tiles sharing one B fragment per K-step.
template<int K, int N>
__global__ __launch_bounds__(256) void gemm_gx(const unsigned short* __restrict__ A,
                                               const unsigned short* __restrict__ W,
                                               const float* __restrict__ bias,
                                               unsigned short* __restrict__ outT) {
    constexpr int TN = N / 16;
    int slot = threadIdx.x >> 6, l = threadIdx.x & 63;
    int wv = blockIdx.x * 4 + slot;
    int tg = wv / TN;               // 64-row group (rows stay within one batch: 512%64==0)
    int tn = wv % TN;
    int rowb = tg * 64;
    int col = tn * 16 + (l & 15);
    int kq = (l >> 4) * 8;
    f32x4 acc0 = {0,0,0,0}, acc1 = {0,0,0,0}, acc2 = {0,0,0,0}, acc3 = {0,0,0,0};
    const unsigned short* wp = W + (size_t)col * K + kq;
    const unsigned short* ap = A + ((size_t)rowb + (l & 15)) * K + kq;
#pragma unroll
    for (int kk = 0; kk < K; kk += 32) {
        short8 bfrag = *(const short8*)(wp + kk);
        short8 a0 = *(const short8*)(ap + kk);
        short8 a1 = *(const short8*)(ap + (size_t)16 * K + kk);
        short8 a2 = *(const short8*)(ap + (size_t)32 * K + kk);
        short8 a3 = *(const short8*)(ap + (size_t)48 * K + kk);
        acc0 = __builtin_amdgcn_mfma_f32_16x16x32_bf16(a0, bfrag, acc0, 0, 0, 0);
        acc1 = __builtin_amdgcn_mfma_f32_16x16x32_bf16(a1, bfrag, acc1, 0, 0, 0);
        acc2 = __builtin_amdgcn_mfma_f32_16x16x32_bf16(a2, bfrag, acc2, 0, 0, 0);
        acc3 = __builtin_amdgcn_mfma_f32_16x16x32_bf16(a3, bfrag, acc3, 0, 0, 0);
    }
    float bv = bias[col];
    int b = rowb >> 9;                       // row / 512
    int tbase = (rowb & 511) + (l >> 4) * 4; // time base for acc element 0
    bool rev = (col >= N / 2);               // wave-uniform (TN/2 divides tile cols)
    unsigned short* rowp = outT + ((size_t)b * N + col) * T_SZ;
#define STORE_ACC(ACC, I) { \
        int tl = tbase + 16 * (I); \
        if (!rev) { us4 v_ = { f2bf(ACC[0]+bv), f2bf(ACC[1]+bv), f2bf(ACC[2]+bv), f2bf(ACC[3]+bv) }; \
                    *(us4*)(rowp + tl) = v_; } \
        else      { us4 v_ = { f2bf(ACC[3]+bv), f2bf(ACC[2]+bv), f2bf(ACC[1]+bv), f2bf(ACC[0]+bv) }; \
                    *(us4*)(rowp + (T_SZ - 4 - tl)) = v_; } }
    STORE_ACC(acc0, 0) STORE_ACC(acc1, 1) STORE_ACC(acc2, 2) STORE_ACC(acc3, 3)
#undef STORE_ACC
}

// ---------------- LSTM scan: one wave per (batch, direction), wave-synchronous ----------------
// gxT: bf16 [b][8H][T], bwd rows time-reversed (so always read forward).
// hout: bf16 [M][2H] (cols 0..H-1 fwd, H..2H-1 bwd), at ORIGINAL time positions.
template<int H>
__global__ __launch_bounds__(256, 1) void lstm_scan(const unsigned short* __restrict__ gxT,
                                                    const float* __restrict__ whhf,
                                                    const float* __restrict__ whhb,
                                                    unsigned short* __restrict__ hout) {
    constexpr int T = T_SZ;
    constexpr int G4 = 4 * H, G8 = 8 * H, OW = 2 * H;
    int l = threadIdx.x & 63, slot = threadIdx.x >> 6;
    int wv = blockIdx.x * 4 + slot;          // 0..1023
    int b = wv >> 1, dir = wv & 1;
    const float* whh = dir ? whhb : whhf;
    __shared__ float hs[4][32];

    int rA, j, q = 0;
    if constexpr (H == 32)      { rA = l;      j = l & 31; }
    else if constexpr (H == 16) { rA = l;      j = l & 15; q = l >> 4; }
    else                        { rA = l & 31; j = l & 7;  q = (l >> 3) & 3; }

    // recurrent weights pinned in VGPRs via vector loads (rows are 16B-aligned for all H)
    float4 wAv[H / 4];
    const float4* wrA = (const float4*)(whh + rA * H);
#pragma unroll
    for (int k = 0; k < H / 4; k++) wAv[k] = wrA[k];
    float4 wBv[(H == 32) ? 8 : 1];
    if constexpr (H == 32) {
        const float4* wrB = (const float4*)(whh + (64 + rA) * H);
#pragma unroll
        for (int k = 0; k < 8; k++) wBv[k] = wrB[k];
    }

    if (l < 32) hs[slot][l] = 0.f;
    __builtin_amdgcn_wave_barrier();

    const unsigned short* gpA = gxT + ((size_t)b * G8 + (size_t)dir * G4 + rA) * T;
    const unsigned short* gpB = gpA + (size_t)64 * T;   // H==32 second gate row

    float c = 0.f;
    short8 bufA = *(const short8*)gpA;
    short8 bufB;
    if constexpr (H == 32) bufB = *(const short8*)gpB;

    bool wr = (H == 32) ? (l < 32) : (H == 16) ? (l < 16) : (l < 8);
    size_t obase = (size_t)b * T * OW + (size_t)dir * H + j;

    for (int ch = 0; ch < T / 8; ch++) {
        short8 curA = bufA, curB;
        if constexpr (H == 32) curB = bufB;
        if (ch + 1 < T / 8) {                // prefetch next 8-step chunk
            bufA = *(const short8*)(gpA + (ch + 1) * 8);
            if constexpr (H == 32) bufB = *(const short8*)(gpB + (ch + 1) * 8);
        }
#pragma unroll
        for (int u = 0; u < 8; u++) {
            int s = ch * 8 + u;
            float g0 = bf2f((unsigned short)curA[u]);
            float g1 = 0.f;
            if constexpr (H == 32) g1 = bf2f((unsigned short)curB[u]);

            float hv[32];
#pragma unroll
            for (int k = 0; k < H; k += 4) {
                float4 v = *(const float4*)&hs[slot][k];
                hv[k] = v.x; hv[k + 1] = v.y; hv[k + 2] = v.z; hv[k + 3] = v.w;
            }
            if constexpr (H == 32) {
                float s0=0,s1=0,s2=0,s3=0,t0=0,t1=0,t2=0,t3=0;
#pragma unroll
                for (int k = 0; k < 8; k++) {
                    float4 wa = wAv[k], wb = wBv[k];
                    s0 = fmaf(wa.x, hv[4*k],   s0); s1 = fmaf(wa.y, hv[4*k+1], s1);
                    s2 = fmaf(wa.z, hv[4*k+2], s2); s3 = fmaf(wa.w, hv[4*k+3], s3);
                    t0 = fmaf(wb.x, hv[4*k],   t0); t1 = fmaf(wb.y, hv[4*k+1], t1);
                    t2 = fmaf(wb.z, hv[4*k+2], t2); t3 = fmaf(wb.w, hv[4*k+3], t3);
                }
                g0 += (s0 + s1) + (s2 + s3);
                g1 += (t0 + t1) + (t2 + t3);
            } else {
                float s0=0,s1=0,s2=0,s3=0;
#pragma unroll
                for (int k = 0; k < H / 4; k++) {
                    float4 wa = wAv[k];
                    s0 = fmaf(wa.x, hv[4*k],   s0); s1 = fmaf(wa.y, hv[4*k+1], s1);
                    s2 = fmaf(wa.z, hv[4*k+2], s2); s3 = fmaf(wa.w, hv[4*k+3], s3);
                }
                g0 += (s0 + s1) + (s2 + s3);
            }

            float iv, fv, gv, ov;
            if constexpr (H == 32) {
                // lanes 0-31: aA=i(sigm), aB=g(tanh); lanes 32-63: aA=f(sigm), aB=o(sigm)
                float aA = sigm_(g0);
                bool up = (l >= 32);
                float g1c = fminf(fmaxf(g1, -15.f), 15.f);
                float ee = __expf(up ? -g1 : 2.f * g1c);
                float r = rcp_(1.f + ee);
                float aB = up ? r : (ee - 1.f) * r;
                float xA = __shfl_xor(aA, 32, 64);
                float xB = __shfl_xor(aB, 32, 64);
                iv = up ? xA : aA;
                fv = up ? aA : xA;
                gv = up ? xB : aB;
                ov = up ? aB : xB;
            } else {
                // one gate per lane; quarter q in {0,1,2,3} = {i,f,g,o}
                float g0c = fminf(fmaxf(g0, -15.f), 15.f);
                float ee = __expf(q == 2 ? 2.f * g0c : -g0);
                float r = rcp_(1.f + ee);
                float a = (q == 2) ? (ee - 1.f) * r : r;
                constexpr int sh = H;  // 16 or 8
                float v1 = __shfl_xor(a, sh, 64);       // q^1
                float v2 = __shfl_xor(a, 2 * sh, 64);   // q^2
                float v3 = __shfl_xor(a, 3 * sh, 64);   // q^3
                iv = q == 0 ? a  : q == 1 ? v1 : q == 2 ? v2 : v3;
                fv = q == 0 ? v1 : q == 1 ? a  : q == 2 ? v3 : v2;
                gv = q == 0 ? v2 : q == 1 ? v3 : q == 2 ? a  : v1;
                ov = q == 0 ? v3 : q == 1 ? v2 : q == 2 ? v1 : a;
            }

            c = fmaf(fv, c, iv * gv);
            float h = ov * tanh_s(c);

            if (wr) {
                hs[slot][j] = h;
                int t = dir ? (T - 1 - s) : s;
                hout[obase + (size_t)t * OW] = f2bf(h);
            }
            __builtin_amdgcn_wave_barrier();
        }
    }
}

// ---------------- FC + softmax over time axis (dim=1) ----------------
__global__ __launch_bounds__(256) void fc_softmax(const unsigned short* __restrict__ h3,
                                                  const float* __restrict__ fcw,
                                                  const float* __restrict__ fcb,
                                                  float* __restrict__ out) {
    constexpr int T = T_SZ;
    __shared__ float ez[T][6];
    __shared__ float ps[256][6];
    __shared__ float wf[6][16];
    __shared__ float bb[6];
    int b = blockIdx.x, tid = threadIdx.x;
    if (tid < 96) wf[tid >> 4][tid & 15] = fcw[tid];
    if (tid < 6) bb[tid] = fcb[tid];
    __syncthreads();
#pragma unroll
    for (int ii = 0; ii < 2; ii++) {
        int t = tid + ii * 256;
        const unsigned short* hp = h3 + ((size_t)b * T + t) * 16;
        float hv[16];
#pragma unroll
        for (int k = 0; k < 16; k++) hv[k] = bf2f(hp[k]);
#pragma unroll
        for (int cc = 0; cc < 6; cc++) {
            float z = bb[cc];
#pragma unroll
            for (int k = 0; k < 16; k++) z = fmaf(hv[k], wf[cc][k], z);
            ez[t][cc] = __expf(z);   // |z| <= ~4.5, no overflow; max-subtract not needed
        }
    }
    __syncthreads();
#pragma unroll
    for (int cc = 0; cc < 6; cc++) ps[tid][cc] = ez[tid][cc] + ez[tid + 256][cc];
    __syncthreads();
    for (int s = 128; s > 0; s >>= 1) {
        if (tid < s) {
#pragma unroll
            for (int cc = 0; cc < 6; cc++) ps[tid][cc] += ps[tid + s][cc];
        }
        __syncthreads();
    }
    float rs[6];
#pragma unroll
    for (int cc = 0; cc < 6; cc++) rs[cc] = rcp_(ps[0][cc]);
#pragma unroll
    for (int ii = 0; ii < 2; ii++) {
        int t = tid + ii * 256;
        float* op = out + ((size_t)b * T + t) * 6;
#pragma unroll
        for (int cc = 0; cc < 6; cc++) op[cc] = ez[t][cc] * rs[cc];
    }
}

// ---------------- launch ----------------
extern "C" void kernel_launch(void* const* d_in, const int* in_sizes, int n_in,
                              void* d_out, int out_size, void* d_ws, size_t ws_size,
                              hipStream_t stream) {
    const float* x     = (const float*)d_in[0];
    const float* whh1f = (const float*)d_in[2];
    const float* whh1b = (const float*)d_in[6];
    const float* whh2f = (const float*)d_in[10];
    const float* whh2b = (const float*)d_in[14];
    const float* whh3f = (const float*)d_in[18];
    const float* whh3b = (const float*)d_in[22];
    const float* fcw   = (const float*)d_in[25];
    const float* fcb   = (const float*)d_in[26];

    char* ws = (char*)d_ws;
    size_t off = 0;
    auto alloc = [&](size_t bytes) -> char* {
        char* p = ws + off; off += (bytes + 255) & ~(size_t)255; return p;
    };
    unsigned short* xbf = (unsigned short*)alloc((size_t)M_SZ * 128 * 2);
    unsigned short* gx  = (unsigned short*)alloc((size_t)M_SZ * 256 * 2);
    unsigned short* h1  = (unsigned short*)alloc((size_t)M_SZ * 64 * 2);
    unsigned short* h2  = (unsigned short*)alloc((size_t)M_SZ * 32 * 2);
    unsigned short* h3  = (unsigned short*)alloc((size_t)M_SZ * 16 * 2);
    unsigned short* wc1 = (unsigned short*)alloc(256 * 128 * 2);
    unsigned short* wc2 = (unsigned short*)alloc(128 * 64 * 2);
    unsigned short* wc3 = (unsigned short*)alloc(64 * 32 * 2);
    float* bs1 = (float*)alloc(256 * 4);
    float* bs2 = (float*)alloc(128 * 4);
    float* bs3 = (float*)alloc(64 * 4);

    prep_layer<<<16, 256, 0, stream>>>((const float*)d_in[1], (const float*)d_in[5],
                                       (const float*)d_in[3], (const float*)d_in[4],
                                       (const float*)d_in[7], (const float*)d_in[8],
                                       wc1, bs1, 128 * 128, 128);
    prep_layer<<<16, 256, 0, stream>>>((const float*)d_in[9], (const float*)d_in[13],
                                       (const float*)d_in[11], (const float*)d_in[12],
                                       (const float*)d_in[15], (const float*)d_in[16],
                                       wc2, bs2, 64 * 64, 64);
    prep_layer<<<16, 256, 0, stream>>>((const float*)d_in[17], (const float*)d_in[21],
                                       (const float*)d_in[19], (const float*)d_in[20],
                                       (const float*)d_in[23], (const float*)d_in[24],
                                       wc3, bs3, 32 * 32, 32);

    cast_x_kernel<<<(M_SZ * 128 / 8 + 255) / 256, 256, 0, stream>>>(x, xbf, M_SZ * 128 / 8);

    // Layer 1: K=128, 8H=256
    gemm_gx<128, 256><<<(M_SZ / 64) * 16 / 4, 256, 0, stream>>>(xbf, wc1, bs1, gx);
    lstm_scan<32><<<256, 256, 0, stream>>>(gx, whh1f, whh1b, h1);
    // Layer 2: K=64, 8H=128
    gemm_gx<64, 128><<<(M_SZ / 64) * 8 / 4, 256, 0, stream>>>(h1, wc2, bs2, gx);
    lstm_scan<16><<<256, 256, 0, stream>>>(gx, whh2f, whh2b, h2);
    // Layer 3: K=32, 8H=64
    gemm_gx<32, 64><<<(M_SZ / 64) * 4 / 4, 256, 0, stream>>>(h2, wc3, bs3, gx);
    lstm_scan<8><<<256, 256, 0, stream>>>(gx, whh3f, whh3b, h3);

    fc_softmax<<<B_SZ, 256, 0, stream>>>(h3, fcw, fcb, (float*)d_out);
}